// Round 14
// baseline (4736.407 us; speedup 1.0000x reference)
//
#include <hip/hip_runtime.h>
#include <hip/hip_bf16.h>
#include <cstddef>

#define S_LEN 512
#define BATCH 64
#define HID 256
#define G3 768
#define SB (S_LEN*BATCH)
#define D2 512
#define L2E 1.44269504f

typedef unsigned short u16;
typedef _Float16 h2v __attribute__((ext_vector_type(2)));
typedef __attribute__((ext_vector_type(8))) short s16x8;
typedef __attribute__((ext_vector_type(4))) float f32x4;

__device__ __forceinline__ float bf2f(u16 u) {
    return __uint_as_float(((unsigned)u) << 16);
}
__device__ __forceinline__ u16 f2bf(float f) {
    unsigned u = __float_as_uint(f);
    unsigned r = (u + 0x7FFFu + ((u >> 16) & 1u)) >> 16;
    return (u16)r;
}
__device__ __forceinline__ u16 f2h_bits(float f) {
    _Float16 h = (_Float16)f;
    union { _Float16 h; u16 u; } cv; cv.h = h;
    return cv.u;
}
__device__ __forceinline__ h2v u2h(unsigned u) {
    union { unsigned u; h2v h; } cv; cv.u = u;
    return cv.h;
}
__device__ __forceinline__ float dot2f(unsigned w, unsigned h, float acc) {
#if __has_builtin(__builtin_amdgcn_fdot2)
    return __builtin_amdgcn_fdot2(u2h(w), u2h(h), acc, false);
#else
    h2v wv = u2h(w), hv = u2h(h);
    return acc + (float)wv.x * (float)hv.x + (float)wv.y * (float)hv.y;
#endif
}
__device__ __forceinline__ float fast_rcp(float x) {
#if __has_builtin(__builtin_amdgcn_rcpf)
    return __builtin_amdgcn_rcpf(x);
#else
    return 1.f / x;
#endif
}
__device__ __forceinline__ float fast_exp2(float x) {
#if __has_builtin(__builtin_amdgcn_exp2f)
    return __builtin_amdgcn_exp2f(x);
#else
    return __expf(x * 0.69314718f);
#endif
}
__device__ __forceinline__ void gload_lds16(const void* g, void* l) {
    __builtin_amdgcn_global_load_lds((const __attribute__((address_space(1))) void*)g,
                                     (__attribute__((address_space(3))) void*)l, 16, 0, 0);
}

// ---------- prep kernels ----------
__global__ void f32_to_bf16(const float* __restrict__ in, u16* __restrict__ out, long n) {
    long i = (long)blockIdx.x * 256 + threadIdx.x;
    if (i < n) out[i] = f2bf(in[i]);
}
// w_ih scaled: gate rows g<512 ×log2e, g>=512 ×2log2e (exp2 prescale)
__global__ void f32_to_bf16_gs(const float* __restrict__ in, u16* __restrict__ out,
                               long n, int K) {
    long i = (long)blockIdx.x * 256 + threadIdx.x;
    if (i >= n) return;
    int g = (int)((i / K) % 768);
    float sc = (g < 512) ? L2E : (2.f * L2E);
    out[i] = f2bf(in[i] * sc);
}
// Quad k-split pack: wpack4[mat][j][1024] u32, tid -> unit=tid>>2, p=tid&3.
// j in [0,96): gsel=j/32 (0=r,1=z,2=n), jj=j%32, ii=jj/4, m=jj%4.
// Rotation folded into packing: chunk c=(ii+2p)&7, k = 64p + 8c + 2m.
// u32 = half2(W[gate][k], W[gate][k+1]) * gate_scale.
__global__ void pack_whh_quad(const float* __restrict__ in, unsigned* __restrict__ out,
                              long total) {
    long i = (long)blockIdx.x * 256 + threadIdx.x;
    if (i >= total) return;
    long mat = i / (96L * 1024);
    long rem = i - mat * (96L * 1024);
    int j = (int)(rem / 1024);
    int tid = (int)(rem - (long)j * 1024);
    int unit = tid >> 2, p = tid & 3;
    int gsel = j / 32, jj = j % 32, ii = jj / 4, m = jj % 4;
    int c = (ii + 2 * p) & 7;
    int k = 64 * p + 8 * c + 2 * m;
    int gate = gsel * 256 + unit;
    float sc = (gate < 512) ? L2E : (2.f * L2E);
    const float* base = in + mat * (768L * 256) + (long)gate * 256 + k;
    unsigned lo = f2h_bits(base[0] * sc);
    unsigned hi = f2h_bits(base[1] * sc);
    out[i] = lo | (hi << 16);
}
// biasT[l][d][g]: g<512 -> (b_ih+b_hh)*log2e ; g>=512 -> b_ih*2log2e
__global__ void add_bias(const float* __restrict__ bih0, const float* __restrict__ bihl,
                         const float* __restrict__ bhh, float* __restrict__ outb) {
    int i = blockIdx.x * 256 + threadIdx.x;
    if (i >= 6 * 1536) return;
    int l = i / 1536, r = i - l * 1536;
    int g = r % 768;
    float bi = (l == 0) ? bih0[r] : bihl[(l - 1) * 1536 + r];
    outb[i] = (g < 512) ? (bi + bhh[i]) * L2E : bi * (2.f * L2E);
}

// ---------- input GEMM (MFMA) ----------
__global__ __launch_bounds__(256, 2) void gemm_mfma(
    const u16* __restrict__ A,
    const u16* __restrict__ Bt,
    const float* __restrict__ bias,
    u16* __restrict__ Cg,
    int K)
{
    int d = blockIdx.z;
    const u16* Bb = Bt + (size_t)d * 768 * K;
    const float* bi = bias + d * G3;
    u16* Cm = Cg + (size_t)d * SB * G3;

    int n0 = blockIdx.x * 128;
    int m0 = blockIdx.y * 128;
    int tid = threadIdx.x;
    int wave = tid >> 6, lane = tid & 63;
    int wm = wave >> 1, wn = wave & 1;

    __shared__ u16 Asm[128 * 32];
    __shared__ u16 Bsm[128 * 32];

    f32x4 acc[4][4] = {};

    for (int k0 = 0; k0 < K; k0 += 32) {
#pragma unroll
        for (int p = 0; p < 2; p++) {
            int c = p * 256 + wave * 64 + lane;
            int row = c >> 2, kc = c & 3;
            const u16* srcA = A + (size_t)(m0 + row) * K + k0 + kc * 8;
            const u16* srcB = Bb + (size_t)(n0 + row) * K + k0 + kc * 8;
            gload_lds16(srcA, &Asm[(p * 256 + wave * 64) * 8]);
            gload_lds16(srcB, &Bsm[(p * 256 + wave * 64) * 8]);
        }
        __syncthreads();

        s16x8 af[4], bfr[4];
#pragma unroll
        for (int i = 0; i < 4; i++) {
            int arow = wm * 64 + i * 16 + (lane & 15);
            af[i] = *reinterpret_cast<const s16x8*>(&Asm[arow * 32 + (lane >> 4) * 8]);
            int brow = wn * 64 + i * 16 + (lane & 15);
            bfr[i] = *reinterpret_cast<const s16x8*>(&Bsm[brow * 32 + (lane >> 4) * 8]);
        }
#pragma unroll
        for (int i = 0; i < 4; i++)
#pragma unroll
            for (int j = 0; j < 4; j++)
                acc[i][j] = __builtin_amdgcn_mfma_f32_16x16x32_bf16(af[i], bfr[j], acc[i][j], 0, 0, 0);
        __syncthreads();
    }

    int lcol = lane & 15, lrow4 = (lane >> 4) * 4;
#pragma unroll
    for (int i = 0; i < 4; i++) {
#pragma unroll
        for (int j = 0; j < 4; j++) {
            int n = n0 + wn * 64 + j * 16 + lcol;
            float bv = bi[n];
#pragma unroll
            for (int q = 0; q < 4; q++) {
                int m = m0 + wm * 64 + i * 16 + lrow4 + q;
                Cm[(size_t)m * G3 + n] = f2bf(acc[i][j][q] + bv);
            }
        }
    }
}

// ---------- recurrent scan (quad k-split, ONE barrier/step) ----------
// 1024 threads (16 waves, 4/SIMD). Quad tid>>2 = unit, tid&3 = k-quarter.
// Each lane: partials of ALL 3 gates over its 64-k quarter (96 dot2, 96 wgt regs);
// shfl_xor(1)+(2) butterfly -> full accs in every quad lane; GRU update redundant
// in-lane (no cross-wave gate exchange). h f16 double-buffer -> ONE barrier/step.
__global__ __launch_bounds__(1024, 4) void gru_scan(
    const unsigned* __restrict__ wpack4, // [12][96][1024] u32, quad-split layout
    const float* __restrict__ bhh,       // [6][2][768] f32 raw
    const u16* __restrict__ gi,          // [2][SB][768] bf16 prescaled, r/z b_hh folded
    const float* __restrict__ h0,        // [12][64][256] f32
    u16* __restrict__ outc,              // [SB][512] bf16 (scratch on last layer)
    float* __restrict__ finals,          // [12][64][256] f32
    int layer)
{
    int b = blockIdx.x;
    int d = blockIdx.y;
    int tid = threadIdx.x;
    int unit = tid >> 2;
    int p = tid & 3;

    int ld = layer * 2 + d;
    const unsigned* Wp = wpack4 + (size_t)ld * 96 * 1024 + tid;
    const u16* gid = gi + (size_t)d * SB * G3;

    __shared__ alignas(16) _Float16 hbuf[2][HID];   // 1 KB double-buffered h
    __shared__ u16 gi_s[2][G3];                     // 3 KB double-buffered gi

    unsigned wpk[96];
#pragma unroll
    for (int j = 0; j < 96; j++) wpk[j] = Wp[(size_t)j * 1024];

    float hreg = h0[(size_t)ld * BATCH * HID + b * HID + unit];
    float bhn = bhh[(size_t)ld * G3 + 512 + unit] * (2.f * L2E);
    if (p == 0) hbuf[0][unit] = (_Float16)hreg;

    // gi: step0 -> gi_s[0]; step1 -> greg (double-distance prefetch)
    u16 greg = 0;
    {
        int s0 = d ? (S_LEN - 1) : 0;
        if (tid < G3) gi_s[0][tid] = gid[((size_t)s0 * BATCH + b) * G3 + tid];
        int s1 = d ? (S_LEN - 2) : 1;
        if (tid < G3) greg = gid[((size_t)s1 * BATCH + b) * G3 + tid];
    }
    __syncthreads();

    for (int t = 0; t < S_LEN; t++) {
        int s = d ? (S_LEN - 1 - t) : t;
        int par = t & 1;
        // write gi(t+1) (loaded a full step ago); issue load of gi(t+2)
        if (t + 1 < S_LEN && tid < G3) gi_s[par ^ 1][tid] = greg;
        if (t + 2 < S_LEN && tid < G3) {
            int s2 = d ? (s - 2) : (s + 2);
            greg = gid[((size_t)s2 * BATCH + b) * G3 + tid];
        }
        // dot over own k-quarter, 3 gate chains; LDS chunks rotated per p
        // (rotation pre-folded into weight packing, wpk indices compile-time)
        const char* hb = (const char*)&hbuf[par][0] + p * 128;
        float a0 = 0.f, a1 = 0.f, a2 = 0.f;
#pragma unroll
        for (int ii = 0; ii < 8; ii++) {
            uint4 q = *(const uint4*)(hb + (((ii + 2 * p) & 7) << 4));
            int jb = 4 * ii;
            a0 = dot2f(wpk[jb + 0], q.x, a0);
            a0 = dot2f(wpk[jb + 1], q.y, a0);
            a0 = dot2f(wpk[jb + 2], q.z, a0);
            a0 = dot2f(wpk[jb + 3], q.w, a0);
            a1 = dot2f(wpk[32 + jb + 0], q.x, a1);
            a1 = dot2f(wpk[32 + jb + 1], q.y, a1);
            a1 = dot2f(wpk[32 + jb + 2], q.z, a1);
            a1 = dot2f(wpk[32 + jb + 3], q.w, a1);
            a2 = dot2f(wpk[64 + jb + 0], q.x, a2);
            a2 = dot2f(wpk[64 + jb + 1], q.y, a2);
            a2 = dot2f(wpk[64 + jb + 2], q.z, a2);
            a2 = dot2f(wpk[64 + jb + 3], q.w, a2);
        }
        // quad butterfly: every quad lane gets full r/z/n accs
        a0 += __shfl_xor(a0, 1, 64); a0 += __shfl_xor(a0, 2, 64);
        a1 += __shfl_xor(a1, 1, 64); a1 += __shfl_xor(a1, 2, 64);
        a2 += __shfl_xor(a2, 1, 64); a2 += __shfl_xor(a2, 2, 64);
        // gate math, redundant across the quad (all in-lane)
        float gir = bf2f(gi_s[par][unit]);
        float giz = bf2f(gi_s[par][256 + unit]);
        float gin = bf2f(gi_s[par][512 + unit]);
        float r = fast_rcp(1.f + fast_exp2(-(gir + a0)));
        float z = fast_rcp(1.f + fast_exp2(-(giz + a1)));
        float xn2 = gin + r * (a2 + bhn);
        float n = 1.f - 2.f * fast_rcp(fast_exp2(xn2) + 1.f);
        float hn = n + z * (hreg - n);
        hreg = hn;
        if (p == 0) hbuf[par ^ 1][unit] = (_Float16)hn;
        if (p == 1) outc[((size_t)s * BATCH + b) * D2 + d * HID + unit] = f2bf(hn);
        // ONE barrier: h(t+1) + gi(t+1) writes visible; lgkm-only (greg load is
        // auto-waited by the compiler at next step's ds_write)
        asm volatile("s_waitcnt lgkmcnt(0)" ::: "memory");
        __builtin_amdgcn_s_barrier();
        __builtin_amdgcn_sched_barrier(0);
    }
    if (p == 0)
        finals[(size_t)ld * BATCH * HID + b * HID + unit] = hreg;
}

extern "C" void kernel_launch(void* const* d_in, const int* in_sizes, int n_in,
                              void* d_out, int out_size, void* d_ws, size_t ws_size,
                              hipStream_t stream) {
    const float* x     = (const float*)d_in[0];
    const float* h0    = (const float*)d_in[1];
    const float* w_ih0 = (const float*)d_in[2];
    const float* b_ih0 = (const float*)d_in[3];
    const float* w_ih  = (const float*)d_in[4];
    const float* b_ih  = (const float*)d_in[5];
    const float* w_hh  = (const float*)d_in[6];
    const float* b_hh  = (const float*)d_in[7];
    float* out = (float*)d_out;

    char* ws = (char*)d_ws;
    // wpack4 u32 [12][96][1024]   @ 0           4,718,592
    // wbf0  bf16 [2][768][128]    @ 4,718,592     393,216
    // wbfl  bf16 [5][2][768][512] @ 5,111,808   7,864,320
    // biasT f32 [6][2][768]       @ 12,976,128     36,864
    // gi    bf16 [2][SB][768]     @ 13,012,992 100,663,296
    // curA  bf16 [SB][512]        @ 113,676,288 33,554,432
    // curB  bf16 [SB][512]        @ 147,230,720 33,554,432
    unsigned* wpack4 = (unsigned*)(ws + 0);
    u16* wbf0  = (u16*)(ws + 4718592);
    u16* wbfl  = (u16*)(ws + 5111808);
    float* biasT = (float*)(ws + 12976128);
    u16* gi    = (u16*)(ws + 13012992);
    u16* curA  = (u16*)(ws + 113676288);
    u16* curB  = (u16*)(ws + 147230720);

    pack_whh_quad<<<(1179648 + 255) / 256, 256, 0, stream>>>(w_hh, wpack4, 1179648L);
    f32_to_bf16_gs<<<(196608 + 255) / 256, 256, 0, stream>>>(w_ih0, wbf0, 196608L, 128);
    f32_to_bf16_gs<<<(3932160 + 255) / 256, 256, 0, stream>>>(w_ih, wbfl, 3932160L, 512);
    f32_to_bf16<<<(4194304 + 255) / 256, 256, 0, stream>>>(x, curA, 4194304L);
    add_bias<<<(9216 + 255) / 256, 256, 0, stream>>>(b_ih0, b_ih, b_hh, biasT);

    u16* cin = curA;
    u16* cout_ = curB;
    for (int l = 0; l < 6; l++) {
        int K = l ? 512 : 128;
        const u16* wt = l ? (wbfl + (size_t)(l - 1) * 2 * 768 * 512) : wbf0;
        const float* bi = biasT + (size_t)l * 1536;
        dim3 g(6, 256, 2);
        gemm_mfma<<<g, 256, 0, stream>>>(cin, wt, bi, gi, K);
        gru_scan<<<dim3(64, 2), 1024, 0, stream>>>(wpack4, b_hh, gi, h0,
                                                   cout_, out, l);
        u16* tmp = cin; cin = cout_; cout_ = tmp;
    }
}